// Round 3
// baseline (181.279 us; speedup 1.0000x reference)
//
#include <hip/hip_runtime.h>

// CIN forward: B=2048, F=32, DIM=64, layers (128,128)
// out[b, 0:64]   = sum_d relu(W0 @ z0 + b0)[64:128, d]
// out[b, 64:192] = sum_d relu(W1 @ z1 + b1)[0:128, d]
// z0[h*32+m, d] = x[h,d]*x[m,d];  z1[h*32+m, d] = h1[h,d]*x[m,d]
//
// R3: 32x32x16_f16 MFMA, 64x64 output per wave (2 rt x 2 ct, 64 acc VGPRs),
// 2 batches per block (W L2-traffic unchanged vs R2), pre-duplicated (s,s)
// scalar table in LDS (ds_read_b32 broadcast, no pack), B-frag = 4 pk_mul.

#define K0 1024
#define K1 2048
#define OUTC 192
#define L0_ELEMS (128 * K0)      // 131072
#define L1_ELEMS (128 * K1)      // 262144
#define L0_FRAGS (L0_ELEMS / 8)  // 16384
#define L1_FRAGS (L1_ELEMS / 8)  // 32768

typedef _Float16 v8h  __attribute__((ext_vector_type(8)));
typedef _Float16 v2h  __attribute__((ext_vector_type(2)));
typedef float    v16f __attribute__((ext_vector_type(16)));

// Swizzled W (f16): frag t = ks*256 + rt*64 + lane holds
//   W[row = rt*32 + (lane&31)][k = ks*16 + (lane>>5)*8 + j],  j=0..7
// stored at wsw[t*8 + j]. Layer 1 appended at +L0_ELEMS.
__global__ void convert_w_kernel(const float* __restrict__ W0,
                                 const float* __restrict__ W1,
                                 _Float16* __restrict__ wsw) {
    int t = blockIdx.x * blockDim.x + threadIdx.x;
    if (t >= L0_FRAGS + L1_FRAGS) return;
    const float* src;
    _Float16* dst;
    if (t < L0_FRAGS) {
        int lane = t & 63, rt = (t >> 6) & 3, ks = t >> 8;
        int row = rt * 32 + (lane & 31);
        int k   = ks * 16 + (lane >> 5) * 8;
        src = W0 + (size_t)row * K0 + k;
        dst = wsw + (size_t)t * 8;
    } else {
        int u = t - L0_FRAGS;
        int lane = u & 63, rt = (u >> 6) & 3, ks = u >> 8;
        int row = rt * 32 + (lane & 31);
        int k   = ks * 16 + (lane >> 5) * 8;
        src = W1 + (size_t)row * K1 + k;
        dst = wsw + L0_ELEMS + (size_t)u * 8;
    }
    #pragma unroll
    for (int j = 0; j < 8; ++j) dst[j] = (_Float16)src[j];
}

__device__ __forceinline__ v8h dup8(v2h s) {
    return __builtin_shufflevector(s, s, 0, 1, 0, 1, 0, 1, 0, 1);
}

__global__ __launch_bounds__(256, 3) void cin_kernel(
    const float* __restrict__ X,      // (B, 32, 64) fp32
    const float* __restrict__ b0,     // (128,)
    const float* __restrict__ b1,     // (128,)
    const _Float16* __restrict__ Wsw, // swizzled W0 | W1 (f16)
    float* __restrict__ out)          // (B, 192) fp32
{
    __shared__ uint32_t xDup[2][32 * 64];   // (s,s) pairs: x[h][d], 16 KB
    __shared__ uint32_t h1Dup[2][64 * 64];  // (s,s) pairs: h1[h][d], 32 KB; xT overlaid at init
    __shared__ float biasLds[256];          // b0 | b1

    const int tid  = threadIdx.x;
    const int wave = tid >> 6;
    const int lane = tid & 63;
    const int bi   = wave >> 1;   // batch within block
    const int rw   = wave & 1;    // row-half (0: rows 0-63, 1: rows 64-127)
    const int l31  = lane & 31;
    const int hi   = lane >> 5;   // k-octet / row-group selector
    const size_t bb = (size_t)blockIdx.x * 2;

    if (tid < 128) biasLds[tid] = b0[tid];
    else           biasLds[tid] = b1[tid - 128];

    // ---- stage x: xT (f16, overlaid in h1Dup) + xDup ((s,s) pairs) ----
    const float* xsrc = X + bb * 2048;
    for (int i = tid; i < 4096; i += 256) {
        int bby = i >> 11, loc = i & 2047;
        int m = loc >> 6, d = loc & 63;
        _Float16 h = (_Float16)xsrc[i];
        _Float16* xT = (_Float16*)&h1Dup[bby][0];
        xT[d * 40 + m] = h;
        v2h p = {h, h};
        xDup[bby][m * 64 + d] = __builtin_bit_cast(uint32_t, p);
    }
    __syncthreads();

    // K-invariant B vector parts: xv[c][p] = x[m = p*16 + hi*8 .. +7][d = c*32 + l31]
    v8h xv[2][2];
    {
        const _Float16* xT = (const _Float16*)&h1Dup[bi][0];
        #pragma unroll
        for (int c = 0; c < 2; ++c)
            #pragma unroll
            for (int p = 0; p < 2; ++p)
                xv[c][p] = *(const v8h*)&xT[(c * 32 + l31) * 40 + p * 16 + hi * 8];
    }
    __syncthreads();  // xv read complete before h1Dup (xT overlay) is rewritten

    // ================= layer 0 =================
    v16f acc[2][2];
    #pragma unroll
    for (int rt = 0; rt < 2; ++rt)
        #pragma unroll
        for (int c = 0; c < 2; ++c) acc[rt][c] = (v16f)0.0f;

    {
        const _Float16* Wp = Wsw + (size_t)rw * 1024 + (size_t)lane * 8;
        #pragma unroll 4
        for (int h = 0; h < 32; ++h) {
            v8h a00 = *(const v8h*)(Wp);          // rt0, p0
            v8h a10 = *(const v8h*)(Wp + 512);    // rt1, p0
            v8h a01 = *(const v8h*)(Wp + 2048);   // rt0, p1
            v8h a11 = *(const v8h*)(Wp + 2560);   // rt1, p1
            Wp += 4096;
            v2h s0 = __builtin_bit_cast(v2h, xDup[bi][h * 64 + l31]);
            v2h s1 = __builtin_bit_cast(v2h, xDup[bi][h * 64 + 32 + l31]);
            v8h s80 = dup8(s0), s81 = dup8(s1);
            v8h b00 = s80 * xv[0][0], b01 = s80 * xv[0][1];
            v8h b10 = s81 * xv[1][0], b11 = s81 * xv[1][1];
            acc[0][0] = __builtin_amdgcn_mfma_f32_32x32x16_f16(a00, b00, acc[0][0], 0, 0, 0);
            acc[1][0] = __builtin_amdgcn_mfma_f32_32x32x16_f16(a10, b00, acc[1][0], 0, 0, 0);
            acc[0][1] = __builtin_amdgcn_mfma_f32_32x32x16_f16(a00, b10, acc[0][1], 0, 0, 0);
            acc[1][1] = __builtin_amdgcn_mfma_f32_32x32x16_f16(a10, b10, acc[1][1], 0, 0, 0);
            acc[0][0] = __builtin_amdgcn_mfma_f32_32x32x16_f16(a01, b01, acc[0][0], 0, 0, 0);
            acc[1][0] = __builtin_amdgcn_mfma_f32_32x32x16_f16(a11, b01, acc[1][0], 0, 0, 0);
            acc[0][1] = __builtin_amdgcn_mfma_f32_32x32x16_f16(a01, b11, acc[0][1], 0, 0, 0);
            acc[1][1] = __builtin_amdgcn_mfma_f32_32x32x16_f16(a11, b11, acc[1][1], 0, 0, 0);
        }
    }

    // ---- epilogue 0 ----
    if (rw == 0) {
        // rows 0..63 -> h1Dup[bi] as (s,s) pairs
        #pragma unroll
        for (int rt = 0; rt < 2; ++rt)
            #pragma unroll
            for (int reg = 0; reg < 16; ++reg) {
                int row = rt * 32 + (reg & 3) + 8 * (reg >> 2) + 4 * hi;
                float bias = biasLds[row];
                #pragma unroll
                for (int c = 0; c < 2; ++c) {
                    float v = acc[rt][c][reg] + bias;
                    v = v > 0.0f ? v : 0.0f;
                    _Float16 hv = (_Float16)v;
                    v2h p = {hv, hv};
                    h1Dup[bi][row * 64 + c * 32 + l31] = __builtin_bit_cast(uint32_t, p);
                }
            }
    } else {
        // rows 64..127 -> out[b][row-64]
        #pragma unroll
        for (int rt = 0; rt < 2; ++rt)
            #pragma unroll
            for (int reg = 0; reg < 16; ++reg) {
                int grow = 64 + rt * 32 + (reg & 3) + 8 * (reg >> 2) + 4 * hi;
                float bias = biasLds[grow];
                float v0 = acc[rt][0][reg] + bias;
                float v1 = acc[rt][1][reg] + bias;
                float s = (v0 > 0.0f ? v0 : 0.0f) + (v1 > 0.0f ? v1 : 0.0f);
                s += __shfl_xor(s, 1);
                s += __shfl_xor(s, 2);
                s += __shfl_xor(s, 4);
                s += __shfl_xor(s, 8);
                s += __shfl_xor(s, 16);
                if (l31 == 0) out[(bb + bi) * OUTC + (grow - 64)] = s;
            }
    }
    __syncthreads();

    // ================= layer 1 =================
    #pragma unroll
    for (int rt = 0; rt < 2; ++rt)
        #pragma unroll
        for (int c = 0; c < 2; ++c) acc[rt][c] = (v16f)0.0f;

    {
        const _Float16* Wp = Wsw + L0_ELEMS + (size_t)rw * 1024 + (size_t)lane * 8;
        #pragma unroll 4
        for (int h = 0; h < 64; ++h) {
            v8h a00 = *(const v8h*)(Wp);
            v8h a10 = *(const v8h*)(Wp + 512);
            v8h a01 = *(const v8h*)(Wp + 2048);
            v8h a11 = *(const v8h*)(Wp + 2560);
            Wp += 4096;
            v2h s0 = __builtin_bit_cast(v2h, h1Dup[bi][h * 64 + l31]);
            v2h s1 = __builtin_bit_cast(v2h, h1Dup[bi][h * 64 + 32 + l31]);
            v8h s80 = dup8(s0), s81 = dup8(s1);
            v8h b00 = s80 * xv[0][0], b01 = s80 * xv[0][1];
            v8h b10 = s81 * xv[1][0], b11 = s81 * xv[1][1];
            acc[0][0] = __builtin_amdgcn_mfma_f32_32x32x16_f16(a00, b00, acc[0][0], 0, 0, 0);
            acc[1][0] = __builtin_amdgcn_mfma_f32_32x32x16_f16(a10, b00, acc[1][0], 0, 0, 0);
            acc[0][1] = __builtin_amdgcn_mfma_f32_32x32x16_f16(a00, b10, acc[0][1], 0, 0, 0);
            acc[1][1] = __builtin_amdgcn_mfma_f32_32x32x16_f16(a10, b10, acc[1][1], 0, 0, 0);
            acc[0][0] = __builtin_amdgcn_mfma_f32_32x32x16_f16(a01, b01, acc[0][0], 0, 0, 0);
            acc[1][0] = __builtin_amdgcn_mfma_f32_32x32x16_f16(a11, b01, acc[1][0], 0, 0, 0);
            acc[0][1] = __builtin_amdgcn_mfma_f32_32x32x16_f16(a01, b11, acc[0][1], 0, 0, 0);
            acc[1][1] = __builtin_amdgcn_mfma_f32_32x32x16_f16(a11, b11, acc[1][1], 0, 0, 0);
        }
    }

    // ---- epilogue 1: all 128 rows -> out[b][64 + row] ----
    #pragma unroll
    for (int rt = 0; rt < 2; ++rt)
        #pragma unroll
        for (int reg = 0; reg < 16; ++reg) {
            int grow = rw * 64 + rt * 32 + (reg & 3) + 8 * (reg >> 2) + 4 * hi;
            float bias = biasLds[128 + grow];
            float v0 = acc[rt][0][reg] + bias;
            float v1 = acc[rt][1][reg] + bias;
            float s = (v0 > 0.0f ? v0 : 0.0f) + (v1 > 0.0f ? v1 : 0.0f);
            s += __shfl_xor(s, 1);
            s += __shfl_xor(s, 2);
            s += __shfl_xor(s, 4);
            s += __shfl_xor(s, 8);
            s += __shfl_xor(s, 16);
            if (l31 == 0) out[(bb + bi) * OUTC + 64 + grow] = s;
        }
}

extern "C" void kernel_launch(void* const* d_in, const int* in_sizes, int n_in,
                              void* d_out, int out_size, void* d_ws, size_t ws_size,
                              hipStream_t stream) {
    const float* X  = (const float*)d_in[0];
    const float* W0 = (const float*)d_in[1];
    const float* b0 = (const float*)d_in[2];
    const float* W1 = (const float*)d_in[3];
    const float* b1 = (const float*)d_in[4];
    float* out = (float*)d_out;
    _Float16* wsw = (_Float16*)d_ws;  // 768 KB

    convert_w_kernel<<<(L0_FRAGS + L1_FRAGS + 255) / 256, 256, 0, stream>>>(W0, W1, wsw);
    cin_kernel<<<1024, 256, 0, stream>>>(X, b0, b1, wsw, out);
}

// Round 4
// 175.129 us; speedup vs baseline: 1.0351x; 1.0351x over previous
//
#include <hip/hip_runtime.h>

// CIN forward: B=2048, F=32, DIM=64, layers (128,128)
// out[b, 0:64]   = sum_d relu(W0 @ z0 + b0)[64:128, d]
// out[b, 64:192] = sum_d relu(W1 @ z1 + b1)[0:128, d]
// z0[h*32+m, d] = x[h,d]*x[m,d];  z1[h*32+m, d] = h1[h,d]*x[m,d]
//
// R4: R3 structure (32x32x16_f16, 64x64/wave, 2 batches/block) with
// non-duplicated u16 scalar tables (in-register dup via lshl_or) to cut LDS
// 50->26 KB -> 4 blocks/CU (launch_bounds(256,4)), zero dispatch tail, and
// tighter B-frag liveness (form -> consume immediately).

#define K0 1024
#define K1 2048
#define OUTC 192
#define L0_ELEMS (128 * K0)      // 131072
#define L1_ELEMS (128 * K1)      // 262144
#define L0_FRAGS (L0_ELEMS / 8)  // 16384
#define L1_FRAGS (L1_ELEMS / 8)  // 32768

typedef _Float16 v8h  __attribute__((ext_vector_type(8)));
typedef _Float16 v2h  __attribute__((ext_vector_type(2)));
typedef float    v16f __attribute__((ext_vector_type(16)));

// Swizzled W (f16): frag t = ks*256 + rt*64 + lane holds
//   W[row = rt*32 + (lane&31)][k = ks*16 + (lane>>5)*8 + j],  j=0..7
__global__ void convert_w_kernel(const float* __restrict__ W0,
                                 const float* __restrict__ W1,
                                 _Float16* __restrict__ wsw) {
    int t = blockIdx.x * blockDim.x + threadIdx.x;
    if (t >= L0_FRAGS + L1_FRAGS) return;
    const float* src;
    _Float16* dst;
    if (t < L0_FRAGS) {
        int lane = t & 63, rt = (t >> 6) & 3, ks = t >> 8;
        int row = rt * 32 + (lane & 31);
        int k   = ks * 16 + (lane >> 5) * 8;
        src = W0 + (size_t)row * K0 + k;
        dst = wsw + (size_t)t * 8;
    } else {
        int u = t - L0_FRAGS;
        int lane = u & 63, rt = (u >> 6) & 3, ks = u >> 8;
        int row = rt * 32 + (lane & 31);
        int k   = ks * 16 + (lane >> 5) * 8;
        src = W1 + (size_t)row * K1 + k;
        dst = wsw + L0_ELEMS + (size_t)u * 8;
    }
    #pragma unroll
    for (int j = 0; j < 8; ++j) dst[j] = (_Float16)src[j];
}

// duplicate a u16 f16 scalar into all 8 lanes of a v8h (1 VALU: lshl_or)
__device__ __forceinline__ v8h dupscalar(uint32_t u) {
    uint32_t pair = (u << 16) | u;
    v2h p = __builtin_bit_cast(v2h, pair);
    return __builtin_shufflevector(p, p, 0, 1, 0, 1, 0, 1, 0, 1);
}

__global__ __launch_bounds__(256, 4) void cin_kernel(
    const float* __restrict__ X,      // (B, 32, 64) fp32
    const float* __restrict__ b0,     // (128,)
    const float* __restrict__ b1,     // (128,)
    const _Float16* __restrict__ Wsw, // swizzled W0 | W1 (f16)
    float* __restrict__ out)          // (B, 192) fp32
{
    __shared__ uint16_t xS[2][32 * 64];   // x[m][d] f16 bits, 8 KB
    __shared__ uint16_t h1S[2][64 * 64];  // h1[h][d] f16 bits, 16 KB; xT overlaid at init
    __shared__ float biasLds[256];        // b0 | b1

    const int tid  = threadIdx.x;
    const int wave = tid >> 6;
    const int lane = tid & 63;
    const int bi   = wave >> 1;   // batch within block
    const int rw   = wave & 1;    // row-half (0: rows 0-63, 1: rows 64-127)
    const int l31  = lane & 31;
    const int hi   = lane >> 5;   // k-octet selector
    const size_t bb = (size_t)blockIdx.x * 2;

    if (tid < 128) biasLds[tid] = b0[tid];
    else           biasLds[tid] = b1[tid - 128];

    // ---- stage x: xT (f16 pitch-40, overlaid in h1S) + xS (u16) ----
    const float* xsrc = X + bb * 2048;
    for (int i = tid; i < 4096; i += 256) {
        int bby = i >> 11, loc = i & 2047;
        int m = loc >> 6, d = loc & 63;
        _Float16 h = (_Float16)xsrc[i];
        ((_Float16*)&h1S[bby][0])[d * 40 + m] = h;
        xS[bby][m * 64 + d] = __builtin_bit_cast(uint16_t, h);
    }
    __syncthreads();

    // K-invariant B vector parts: xv[c][p] = x[m = p*16 + hi*8 .. +7][d = c*32 + l31]
    v8h xv[2][2];
    {
        const _Float16* xT = (const _Float16*)&h1S[bi][0];
        #pragma unroll
        for (int c = 0; c < 2; ++c)
            #pragma unroll
            for (int p = 0; p < 2; ++p)
                xv[c][p] = *(const v8h*)&xT[(c * 32 + l31) * 40 + p * 16 + hi * 8];
    }
    __syncthreads();  // xv reads complete before h1S overlay is rewritten

    // ================= layer 0 =================
    v16f acc[2][2];
    #pragma unroll
    for (int rt = 0; rt < 2; ++rt)
        #pragma unroll
        for (int c = 0; c < 2; ++c) acc[rt][c] = (v16f)0.0f;

    {
        const _Float16* Wp = Wsw + (size_t)rw * 1024 + (size_t)lane * 8;
        #pragma unroll 2
        for (int h = 0; h < 32; ++h) {
            v8h a00 = *(const v8h*)(Wp);          // rt0, p0
            v8h a10 = *(const v8h*)(Wp + 512);    // rt1, p0
            v8h a01 = *(const v8h*)(Wp + 2048);   // rt0, p1
            v8h a11 = *(const v8h*)(Wp + 2560);   // rt1, p1
            Wp += 4096;
            uint32_t u0 = xS[bi][h * 64 + l31];
            uint32_t u1 = xS[bi][h * 64 + 32 + l31];
            v8h s80 = dupscalar(u0), s81 = dupscalar(u1);
            v8h b00 = s80 * xv[0][0];
            acc[0][0] = __builtin_amdgcn_mfma_f32_32x32x16_f16(a00, b00, acc[0][0], 0, 0, 0);
            acc[1][0] = __builtin_amdgcn_mfma_f32_32x32x16_f16(a10, b00, acc[1][0], 0, 0, 0);
            v8h b10 = s81 * xv[1][0];
            acc[0][1] = __builtin_amdgcn_mfma_f32_32x32x16_f16(a00, b10, acc[0][1], 0, 0, 0);
            acc[1][1] = __builtin_amdgcn_mfma_f32_32x32x16_f16(a10, b10, acc[1][1], 0, 0, 0);
            v8h b01 = s80 * xv[0][1];
            acc[0][0] = __builtin_amdgcn_mfma_f32_32x32x16_f16(a01, b01, acc[0][0], 0, 0, 0);
            acc[1][0] = __builtin_amdgcn_mfma_f32_32x32x16_f16(a11, b01, acc[1][0], 0, 0, 0);
            v8h b11 = s81 * xv[1][1];
            acc[0][1] = __builtin_amdgcn_mfma_f32_32x32x16_f16(a01, b11, acc[0][1], 0, 0, 0);
            acc[1][1] = __builtin_amdgcn_mfma_f32_32x32x16_f16(a11, b11, acc[1][1], 0, 0, 0);
        }
    }

    // ---- epilogue 0 ----
    if (rw == 0) {
        // rows 0..63 -> h1S[bi] (u16)
        #pragma unroll
        for (int rt = 0; rt < 2; ++rt)
            #pragma unroll
            for (int reg = 0; reg < 16; ++reg) {
                int row = rt * 32 + (reg & 3) + 8 * (reg >> 2) + 4 * hi;
                float bias = biasLds[row];
                #pragma unroll
                for (int c = 0; c < 2; ++c) {
                    float v = acc[rt][c][reg] + bias;
                    v = v > 0.0f ? v : 0.0f;
                    h1S[bi][row * 64 + c * 32 + l31] =
                        __builtin_bit_cast(uint16_t, (_Float16)v);
                }
            }
    } else {
        // rows 64..127 -> out[b][row-64]
        #pragma unroll
        for (int rt = 0; rt < 2; ++rt)
            #pragma unroll
            for (int reg = 0; reg < 16; ++reg) {
                int grow = 64 + rt * 32 + (reg & 3) + 8 * (reg >> 2) + 4 * hi;
                float bias = biasLds[grow];
                float v0 = acc[rt][0][reg] + bias;
                float v1 = acc[rt][1][reg] + bias;
                float s = (v0 > 0.0f ? v0 : 0.0f) + (v1 > 0.0f ? v1 : 0.0f);
                s += __shfl_xor(s, 1);
                s += __shfl_xor(s, 2);
                s += __shfl_xor(s, 4);
                s += __shfl_xor(s, 8);
                s += __shfl_xor(s, 16);
                if (l31 == 0) out[(bb + bi) * OUTC + (grow - 64)] = s;
            }
    }
    __syncthreads();

    // ================= layer 1 =================
    #pragma unroll
    for (int rt = 0; rt < 2; ++rt)
        #pragma unroll
        for (int c = 0; c < 2; ++c) acc[rt][c] = (v16f)0.0f;

    {
        const _Float16* Wp = Wsw + L0_ELEMS + (size_t)rw * 1024 + (size_t)lane * 8;
        #pragma unroll 2
        for (int h = 0; h < 64; ++h) {
            v8h a00 = *(const v8h*)(Wp);
            v8h a10 = *(const v8h*)(Wp + 512);
            v8h a01 = *(const v8h*)(Wp + 2048);
            v8h a11 = *(const v8h*)(Wp + 2560);
            Wp += 4096;
            uint32_t u0 = h1S[bi][h * 64 + l31];
            uint32_t u1 = h1S[bi][h * 64 + 32 + l31];
            v8h s80 = dupscalar(u0), s81 = dupscalar(u1);
            v8h b00 = s80 * xv[0][0];
            acc[0][0] = __builtin_amdgcn_mfma_f32_32x32x16_f16(a00, b00, acc[0][0], 0, 0, 0);
            acc[1][0] = __builtin_amdgcn_mfma_f32_32x32x16_f16(a10, b00, acc[1][0], 0, 0, 0);
            v8h b10 = s81 * xv[1][0];
            acc[0][1] = __builtin_amdgcn_mfma_f32_32x32x16_f16(a00, b10, acc[0][1], 0, 0, 0);
            acc[1][1] = __builtin_amdgcn_mfma_f32_32x32x16_f16(a10, b10, acc[1][1], 0, 0, 0);
            v8h b01 = s80 * xv[0][1];
            acc[0][0] = __builtin_amdgcn_mfma_f32_32x32x16_f16(a01, b01, acc[0][0], 0, 0, 0);
            acc[1][0] = __builtin_amdgcn_mfma_f32_32x32x16_f16(a11, b01, acc[1][0], 0, 0, 0);
            v8h b11 = s81 * xv[1][1];
            acc[0][1] = __builtin_amdgcn_mfma_f32_32x32x16_f16(a01, b11, acc[0][1], 0, 0, 0);
            acc[1][1] = __builtin_amdgcn_mfma_f32_32x32x16_f16(a11, b11, acc[1][1], 0, 0, 0);
        }
    }

    // ---- epilogue 1: all 128 rows -> out[b][64 + row] ----
    #pragma unroll
    for (int rt = 0; rt < 2; ++rt)
        #pragma unroll
        for (int reg = 0; reg < 16; ++reg) {
            int grow = rw * 64 + rt * 32 + (reg & 3) + 8 * (reg >> 2) + 4 * hi;
            float bias = biasLds[128 + grow];
            float v0 = acc[rt][0][reg] + bias;
            float v1 = acc[rt][1][reg] + bias;
            float s = (v0 > 0.0f ? v0 : 0.0f) + (v1 > 0.0f ? v1 : 0.0f);
            s += __shfl_xor(s, 1);
            s += __shfl_xor(s, 2);
            s += __shfl_xor(s, 4);
            s += __shfl_xor(s, 8);
            s += __shfl_xor(s, 16);
            if (l31 == 0) out[(bb + bi) * OUTC + 64 + grow] = s;
        }
}

extern "C" void kernel_launch(void* const* d_in, const int* in_sizes, int n_in,
                              void* d_out, int out_size, void* d_ws, size_t ws_size,
                              hipStream_t stream) {
    const float* X  = (const float*)d_in[0];
    const float* W0 = (const float*)d_in[1];
    const float* b0 = (const float*)d_in[2];
    const float* W1 = (const float*)d_in[3];
    const float* b1 = (const float*)d_in[4];
    float* out = (float*)d_out;
    _Float16* wsw = (_Float16*)d_ws;  // 768 KB

    convert_w_kernel<<<(L0_FRAGS + L1_FRAGS + 255) / 256, 256, 0, stream>>>(W0, W1, wsw);
    cin_kernel<<<1024, 256, 0, stream>>>(X, b0, b1, wsw, out);
}